// Round 5
// baseline (50.123 us; speedup 1.0000x reference)
//
#include <hip/hip_runtime.h>

// MEASUREMENT ROUND: byte-identical round-4 kernel, launched 5x back-to-back
// (idempotent: each launch fully overwrites out). (dur - 14.01)/4 = marginal
// cost of one dispatch = per-node overhead + warm kernel time. Discriminates
// "fixed ~13 us graph floor + ~1.5 us kernel" (Model A) from "~7 us kernel"
// (Model B), which three rounds of structurally different kernels at equal
// dur_us could not.

#define DCOLS 16384
#define SD    128          // K dim == M dim (S = 2+P = nOut)
#define HALF  64           // W rows per build phase
#define NB    64           // output cols per block

typedef float  f32x4  __attribute__((ext_vector_type(4)));
typedef short  bf16x8 __attribute__((ext_vector_type(8)));
typedef unsigned int u32x4 __attribute__((ext_vector_type(4)));

__device__ __forceinline__ unsigned int f2bf(float x) {
    unsigned int u = __builtin_bit_cast(unsigned int, x);
    return (u + 0x7FFFu + ((u >> 16) & 1u)) >> 16;   // RNE; inputs are finite
}

__device__ __forceinline__ const float* frow(int k, const float* loss,
                                             const float* prev,
                                             const float* params) {
    return (k == 0) ? loss : (k == 1) ? prev : params + (size_t)(k - 2) * DCOLS;
}

__global__ __launch_bounds__(256) void fused_edges_mfma(
    const float* __restrict__ loss, const float* __restrict__ prev,
    const float* __restrict__ params, const float* __restrict__ weights,
    const int* __restrict__ src, const int* __restrict__ dst,
    float* __restrict__ out, int E, int S)
{
    __shared__ __align__(16) float          Wf[HALF * SD];   // 32 KB
    __shared__ __align__(16) unsigned short Ft[NB * SD];     // 16 KB

    const int tid  = threadIdx.x;
    const int lane = tid & 63;
    const int wave = tid >> 6;
    const int lr   = lane & 15;
    const int kq   = lane >> 4;
    const int col0 = blockIdx.x * NB;

    // ---------- stage F -> Ft: bf16 [c][k], granule g = (k>>3) ^ (c&7) ----------
    for (int t = tid; t < (SD / 2) * (NB / 4); t += 256) {
        const int kp = t >> 4;
        const int c4 = t & 15;
        const int k0 = kp * 2;
        const float* r0 = frow(k0,     loss, prev, params);
        const float* r1 = frow(k0 + 1, loss, prev, params);
        const f32x4 a = *reinterpret_cast<const f32x4*>(r0 + col0 + c4 * 4);
        const f32x4 b = *reinterpret_cast<const f32x4*>(r1 + col0 + c4 * 4);
        #pragma unroll
        for (int i = 0; i < 4; ++i) {
            const int c = c4 * 4 + i;
            const unsigned int v = f2bf(a[i]) | (f2bf(b[i]) << 16);
            const int g  = (kp >> 2) ^ (c & 7);
            const int by = c * 256 + g * 16 + (kp & 3) * 4;
            *reinterpret_cast<unsigned int*>(reinterpret_cast<char*>(Ft) + by) = v;
        }
    }

    u32x4 areg[2][4];

    #pragma unroll
    for (int ph = 0; ph < 2; ++ph) {
        __syncthreads();
        const f32x4 z = {0.f, 0.f, 0.f, 0.f};
        #pragma unroll
        for (int i = 0; i < (HALF * SD / 4) / 256; ++i)
            *reinterpret_cast<f32x4*>(Wf + (i * 256 + tid) * 4) = z;
        __syncthreads();

        const int lo = S + ph * HALF;
        const int E4 = E & ~3;
        for (int e = tid * 4; e < E4; e += 1024) {
            const int4  s4 = *reinterpret_cast<const int4*>(src + e);
            const int4  d4 = *reinterpret_cast<const int4*>(dst + e);
            const f32x4 w4 = *reinterpret_cast<const f32x4*>(weights + e);
            int r;
            r = d4.x - lo; if ((unsigned)r < HALF) atomicAdd(&Wf[r * SD + ((((s4.x >> 3) ^ (r & 7)) << 3) | (s4.x & 7))], w4.x);
            r = d4.y - lo; if ((unsigned)r < HALF) atomicAdd(&Wf[r * SD + ((((s4.y >> 3) ^ (r & 7)) << 3) | (s4.y & 7))], w4.y);
            r = d4.z - lo; if ((unsigned)r < HALF) atomicAdd(&Wf[r * SD + ((((s4.z >> 3) ^ (r & 7)) << 3) | (s4.z & 7))], w4.z);
            r = d4.w - lo; if ((unsigned)r < HALF) atomicAdd(&Wf[r * SD + ((((s4.w >> 3) ^ (r & 7)) << 3) | (s4.w & 7))], w4.w);
        }
        for (int e = E4 + tid; e < E; e += 256) {
            const int r = dst[e] - lo;
            if ((unsigned)r < HALF) {
                const int k = src[e];
                atomicAdd(&Wf[r * SD + ((((k >> 3) ^ (r & 7)) << 3) | (k & 7))], weights[e]);
            }
        }
        __syncthreads();

        if ((wave >> 1) == ph) {
            const int wl = wave & 1;
            #pragma unroll
            for (int mt = 0; mt < 2; ++mt) {
                const int rr = wl * 32 + mt * 16 + lr;
                #pragma unroll
                for (int kt = 0; kt < 4; ++kt) {
                    const int g = (kt * 4 + kq) ^ (rr & 7);
                    const float* p = Wf + rr * SD + g * 8;
                    const f32x4 x = *reinterpret_cast<const f32x4*>(p);
                    const f32x4 y = *reinterpret_cast<const f32x4*>(p + 4);
                    u32x4 v;
                    v.x = f2bf(x[0]) | (f2bf(x[1]) << 16);
                    v.y = f2bf(x[2]) | (f2bf(x[3]) << 16);
                    v.z = f2bf(y[0]) | (f2bf(y[1]) << 16);
                    v.w = f2bf(y[2]) | (f2bf(y[3]) << 16);
                    areg[mt][kt] = v;
                }
            }
        }
    }
    __syncthreads();

    f32x4 acc[2][4] = {};
    #pragma unroll
    for (int kt = 0; kt < 4; ++kt) {
        bf16x8 bf[4];
        #pragma unroll
        for (int nt = 0; nt < 4; ++nt) {
            const int c = nt * 16 + lr;
            const int g = (kt * 4 + kq) ^ (c & 7);
            bf[nt] = *reinterpret_cast<const bf16x8*>(Ft + c * SD + g * 8);
        }
        #pragma unroll
        for (int mt = 0; mt < 2; ++mt) {
            const bf16x8 af = __builtin_bit_cast(bf16x8, areg[mt][kt]);
            #pragma unroll
            for (int nt = 0; nt < 4; ++nt)
                acc[mt][nt] = __builtin_amdgcn_mfma_f32_16x16x32_bf16(
                    af, bf[nt], acc[mt][nt], 0, 0, 0);
        }
    }

    #pragma unroll
    for (int mt = 0; mt < 2; ++mt) {
        const int nbase = wave * 32 + mt * 16 + kq * 4;
        #pragma unroll
        for (int nt = 0; nt < 4; ++nt) {
            const int d = col0 + nt * 16 + lr;
            #pragma unroll
            for (int r = 0; r < 4; ++r)
                out[(size_t)(nbase + r) * DCOLS + d] = acc[mt][nt][r];
        }
    }
}

extern "C" void kernel_launch(void* const* d_in, const int* in_sizes, int n_in,
                              void* d_out, int out_size, void* d_ws, size_t ws_size,
                              hipStream_t stream) {
    const float* loss    = (const float*)d_in[0];
    const float* prev    = (const float*)d_in[1];
    const float* params  = (const float*)d_in[2];
    const float* weights = (const float*)d_in[3];
    const int*   src     = (const int*)d_in[4];
    const int*   dst     = (const int*)d_in[5];
    float*       out     = (float*)d_out;

    const int E = in_sizes[3];              // 4096
    const int P = in_sizes[2] / DCOLS;      // 126
    const int S = 2 + P;                    // 128

    // 5 identical idempotent launches: (dur - single-launch dur) / 4 gives the
    // exact marginal cost (node overhead + warm kernel) of one dispatch.
    for (int rep = 0; rep < 5; ++rep) {
        fused_edges_mfma<<<DCOLS / NB, 256, 0, stream>>>(
            loss, prev, params, weights, src, dst, out, E, S);
    }
}

// Round 6
// 15.195 us; speedup vs baseline: 3.2986x; 3.2986x over previous
//
#include <hip/hip_runtime.h>

// out[n][d] = sum_k W[n][k] * F[k][d],  n in [0,128), d in [0,16384)
// F = [loss; prev_loss; params] (128 x 16384 fp32). W from 4096 edges:
// W[dst-S][src] += weight for dst >= S (S = 2+126 = 128).
//
// Dense-MFMA, single-phase variant of the verified round-4 kernel:
//  - NB=32 cols/block, grid 512 -> 2 blocks/CU (72 KB LDS each), 2 waves/SIMD
//    of TLP to hide edge-scan / staging latency (R4 had 1 wave/SIMD).
//  - Full 128x128 fp32 W in LDS (64 KB) -> edge list scanned ONCE (R4: twice).
//  - F slice read once from HBM as bf16 [col][k], XOR-swizzled 16B granules.
//  - 3 barriers total. Session model: ~10.7 us harness floor + ~2.5 us kernel.

#define DCOLS 16384
#define SD    128          // K dim == M dim (S = 2+P = nOut)
#define NB    32           // output cols per block

typedef float  f32x4  __attribute__((ext_vector_type(4)));
typedef short  bf16x8 __attribute__((ext_vector_type(8)));
typedef unsigned int u32x4 __attribute__((ext_vector_type(4)));

__device__ __forceinline__ unsigned int f2bf(float x) {
    unsigned int u = __builtin_bit_cast(unsigned int, x);
    return (u + 0x7FFFu + ((u >> 16) & 1u)) >> 16;   // RNE; inputs are finite
}

__device__ __forceinline__ const float* frow(int k, const float* loss,
                                             const float* prev,
                                             const float* params) {
    return (k == 0) ? loss : (k == 1) ? prev : params + (size_t)(k - 2) * DCOLS;
}

__global__ __launch_bounds__(256) void fused_edges_mfma(
    const float* __restrict__ loss, const float* __restrict__ prev,
    const float* __restrict__ params, const float* __restrict__ weights,
    const int* __restrict__ src, const int* __restrict__ dst,
    float* __restrict__ out, int E, int S)
{
    __shared__ __align__(16) float          Wf[SD * SD];   // 64 KB fp32, swizzled granules
    __shared__ __align__(16) unsigned short Ft[NB * SD];   //  8 KB bf16, swizzled granules

    const int tid  = threadIdx.x;
    const int lane = tid & 63;
    const int wave = tid >> 6;
    const int lr   = lane & 15;      // row/col within a 16-tile
    const int kq   = lane >> 4;      // 0..3 quarter-wave
    const int col0 = blockIdx.x * NB;

    // ---------- stage F -> Ft: bf16 [c][k], granule g = (k>>3) ^ (c&7) ----------
    for (int t = tid; t < (SD / 2) * (NB / 4); t += 256) {   // 512 tasks, 2 iters
        const int kp = t >> 3;            // k-pair 0..63
        const int c4 = t & 7;             // col quad 0..7 (low bits -> coalesced)
        const int k0 = kp * 2;
        const float* r0 = frow(k0,     loss, prev, params);
        const float* r1 = frow(k0 + 1, loss, prev, params);
        const f32x4 a = *reinterpret_cast<const f32x4*>(r0 + col0 + c4 * 4);
        const f32x4 b = *reinterpret_cast<const f32x4*>(r1 + col0 + c4 * 4);
        #pragma unroll
        for (int i = 0; i < 4; ++i) {
            const int c = c4 * 4 + i;
            const unsigned int v = f2bf(a[i]) | (f2bf(b[i]) << 16);
            const int g  = (kp >> 2) ^ (c & 7);
            const int by = c * 256 + g * 16 + (kp & 3) * 4;
            *reinterpret_cast<unsigned int*>(reinterpret_cast<char*>(Ft) + by) = v;
        }
    }

    // ---------- zero W ----------
    const f32x4 z = {0.f, 0.f, 0.f, 0.f};
    #pragma unroll
    for (int i = 0; i < (SD * SD / 4) / 256; ++i)            // 16 x f32x4 per thread
        *reinterpret_cast<f32x4*>(Wf + (i * 256 + tid) * 4) = z;
    __syncthreads();

    // ---------- single edge scan: W[r][k] swizzled as r*SD + ((k>>3)^(r&7))*8 + (k&7) ----------
    const int E4 = E & ~3;
    for (int e = tid * 4; e < E4; e += 1024) {
        const int4  s4 = *reinterpret_cast<const int4*>(src + e);
        const int4  d4 = *reinterpret_cast<const int4*>(dst + e);
        const f32x4 w4 = *reinterpret_cast<const f32x4*>(weights + e);
        int r;
        r = d4.x - S; if ((unsigned)r < SD) atomicAdd(&Wf[r * SD + ((((s4.x >> 3) ^ (r & 7)) << 3) | (s4.x & 7))], w4.x);
        r = d4.y - S; if ((unsigned)r < SD) atomicAdd(&Wf[r * SD + ((((s4.y >> 3) ^ (r & 7)) << 3) | (s4.y & 7))], w4.y);
        r = d4.z - S; if ((unsigned)r < SD) atomicAdd(&Wf[r * SD + ((((s4.z >> 3) ^ (r & 7)) << 3) | (s4.z & 7))], w4.z);
        r = d4.w - S; if ((unsigned)r < SD) atomicAdd(&Wf[r * SD + ((((s4.w >> 3) ^ (r & 7)) << 3) | (s4.w & 7))], w4.w);
    }
    for (int e = E4 + tid; e < E; e += 256) {
        const int r = dst[e] - S;
        if ((unsigned)r < SD) {
            const int k = src[e];
            atomicAdd(&Wf[r * SD + ((((k >> 3) ^ (r & 7)) << 3) | (k & 7))], weights[e]);
        }
    }
    __syncthreads();

    // ---------- each wave pulls A fragments for its 32 rows into registers ----------
    u32x4 areg[2][4];
    #pragma unroll
    for (int mt = 0; mt < 2; ++mt) {
        const int rr = wave * 32 + mt * 16 + lr;             // absolute row 0..127
        #pragma unroll
        for (int kt = 0; kt < 4; ++kt) {
            const int g = (kt * 4 + kq) ^ (rr & 7);
            const float* p = Wf + rr * SD + g * 8;           // 8 contiguous fp32 (one granule)
            const f32x4 x = *reinterpret_cast<const f32x4*>(p);
            const f32x4 y = *reinterpret_cast<const f32x4*>(p + 4);
            u32x4 v;
            v.x = f2bf(x[0]) | (f2bf(x[1]) << 16);
            v.y = f2bf(x[2]) | (f2bf(x[3]) << 16);
            v.z = f2bf(y[0]) | (f2bf(y[1]) << 16);
            v.w = f2bf(y[2]) | (f2bf(y[3]) << 16);
            areg[mt][kt] = v;
        }
    }
    __syncthreads();    // Ft staging complete (and Wf reads done)

    // ---------- MFMA: wave w -> out rows [w*32, w*32+32), cols [col0, col0+32) ----------
    f32x4 acc[2][2] = {};
    #pragma unroll
    for (int kt = 0; kt < 4; ++kt) {
        bf16x8 bf[2];
        #pragma unroll
        for (int nt = 0; nt < 2; ++nt) {
            const int c = nt * 16 + lr;
            const int g = (kt * 4 + kq) ^ (c & 7);
            bf[nt] = *reinterpret_cast<const bf16x8*>(Ft + c * SD + g * 8);
        }
        #pragma unroll
        for (int mt = 0; mt < 2; ++mt) {
            const bf16x8 af = __builtin_bit_cast(bf16x8, areg[mt][kt]);
            #pragma unroll
            for (int nt = 0; nt < 2; ++nt)
                acc[mt][nt] = __builtin_amdgcn_mfma_f32_16x16x32_bf16(
                    af, bf[nt], acc[mt][nt], 0, 0, 0);
        }
    }

    // ---------- store (C/D layout: col = lane&15, row = (lane>>4)*4 + reg) ----------
    #pragma unroll
    for (int mt = 0; mt < 2; ++mt) {
        const int nbase = wave * 32 + mt * 16 + kq * 4;
        #pragma unroll
        for (int nt = 0; nt < 2; ++nt) {
            const int d = col0 + nt * 16 + lr;
            #pragma unroll
            for (int r = 0; r < 4; ++r)
                out[(size_t)(nbase + r) * DCOLS + d] = acc[mt][nt][r];
        }
    }
}

extern "C" void kernel_launch(void* const* d_in, const int* in_sizes, int n_in,
                              void* d_out, int out_size, void* d_ws, size_t ws_size,
                              hipStream_t stream) {
    const float* loss    = (const float*)d_in[0];
    const float* prev    = (const float*)d_in[1];
    const float* params  = (const float*)d_in[2];
    const float* weights = (const float*)d_in[3];
    const int*   src     = (const int*)d_in[4];
    const int*   dst     = (const int*)d_in[5];
    float*       out     = (float*)d_out;

    const int E = in_sizes[3];              // 4096
    const int P = in_sizes[2] / DCOLS;      // 126
    const int S = 2 + P;                    // 128

    fused_edges_mfma<<<DCOLS / NB, 256, 0, stream>>>(
        loss, prev, params, weights, src, dst, out, E, S);
}

// Round 7
// 14.030 us; speedup vs baseline: 3.5725x; 1.0830x over previous
//
#include <hip/hip_runtime.h>

// FINAL: byte-identical round-4 kernel (best measured: 14.01 us, absmax 0.125).
// Session model (R5 controlled 5x-launch measurement): dur_us = ~10.7 us
// harness floor (graph base ~5.0 + ~5.7 per-node) + ~3.3 us kernel, vs a
// 2.6 us HBM floor for the kernel's 16 MB of traffic. R3/R6 structural
// variants confirmed the residual ~0.7 us is not recoverable at source level.
//
// out[n][d] = sum_k W[n][k] * F[k][d],  n in [0,128), d in [0,16384)
// Dense-MFMA: 128x128x16384 GEMM, A = W (bf16 from edge scatter), B = F
// (bf16-staged fp32 features), fp32 accumulate, v_mfma_f32_16x16x32_bf16.

#define DCOLS 16384
#define SD    128          // K dim == M dim (S = 2+P = nOut)
#define HALF  64           // W rows per build phase
#define NB    64           // output cols per block

typedef float  f32x4  __attribute__((ext_vector_type(4)));
typedef short  bf16x8 __attribute__((ext_vector_type(8)));
typedef unsigned int u32x4 __attribute__((ext_vector_type(4)));

__device__ __forceinline__ unsigned int f2bf(float x) {
    unsigned int u = __builtin_bit_cast(unsigned int, x);
    return (u + 0x7FFFu + ((u >> 16) & 1u)) >> 16;   // RNE; inputs are finite
}

__device__ __forceinline__ const float* frow(int k, const float* loss,
                                             const float* prev,
                                             const float* params) {
    return (k == 0) ? loss : (k == 1) ? prev : params + (size_t)(k - 2) * DCOLS;
}

__global__ __launch_bounds__(256) void fused_edges_mfma(
    const float* __restrict__ loss, const float* __restrict__ prev,
    const float* __restrict__ params, const float* __restrict__ weights,
    const int* __restrict__ src, const int* __restrict__ dst,
    float* __restrict__ out, int E, int S)
{
    __shared__ __align__(16) float          Wf[HALF * SD];   // 32 KB
    __shared__ __align__(16) unsigned short Ft[NB * SD];     // 16 KB

    const int tid  = threadIdx.x;
    const int lane = tid & 63;
    const int wave = tid >> 6;
    const int lr   = lane & 15;
    const int kq   = lane >> 4;
    const int col0 = blockIdx.x * NB;

    // ---------- stage F -> Ft: bf16 [c][k], granule g = (k>>3) ^ (c&7) ----------
    for (int t = tid; t < (SD / 2) * (NB / 4); t += 256) {
        const int kp = t >> 4;
        const int c4 = t & 15;
        const int k0 = kp * 2;
        const float* r0 = frow(k0,     loss, prev, params);
        const float* r1 = frow(k0 + 1, loss, prev, params);
        const f32x4 a = *reinterpret_cast<const f32x4*>(r0 + col0 + c4 * 4);
        const f32x4 b = *reinterpret_cast<const f32x4*>(r1 + col0 + c4 * 4);
        #pragma unroll
        for (int i = 0; i < 4; ++i) {
            const int c = c4 * 4 + i;
            const unsigned int v = f2bf(a[i]) | (f2bf(b[i]) << 16);
            const int g  = (kp >> 2) ^ (c & 7);
            const int by = c * 256 + g * 16 + (kp & 3) * 4;
            *reinterpret_cast<unsigned int*>(reinterpret_cast<char*>(Ft) + by) = v;
        }
    }

    u32x4 areg[2][4];

    #pragma unroll
    for (int ph = 0; ph < 2; ++ph) {
        __syncthreads();
        const f32x4 z = {0.f, 0.f, 0.f, 0.f};
        #pragma unroll
        for (int i = 0; i < (HALF * SD / 4) / 256; ++i)
            *reinterpret_cast<f32x4*>(Wf + (i * 256 + tid) * 4) = z;
        __syncthreads();

        const int lo = S + ph * HALF;
        const int E4 = E & ~3;
        for (int e = tid * 4; e < E4; e += 1024) {
            const int4  s4 = *reinterpret_cast<const int4*>(src + e);
            const int4  d4 = *reinterpret_cast<const int4*>(dst + e);
            const f32x4 w4 = *reinterpret_cast<const f32x4*>(weights + e);
            int r;
            r = d4.x - lo; if ((unsigned)r < HALF) atomicAdd(&Wf[r * SD + ((((s4.x >> 3) ^ (r & 7)) << 3) | (s4.x & 7))], w4.x);
            r = d4.y - lo; if ((unsigned)r < HALF) atomicAdd(&Wf[r * SD + ((((s4.y >> 3) ^ (r & 7)) << 3) | (s4.y & 7))], w4.y);
            r = d4.z - lo; if ((unsigned)r < HALF) atomicAdd(&Wf[r * SD + ((((s4.z >> 3) ^ (r & 7)) << 3) | (s4.z & 7))], w4.z);
            r = d4.w - lo; if ((unsigned)r < HALF) atomicAdd(&Wf[r * SD + ((((s4.w >> 3) ^ (r & 7)) << 3) | (s4.w & 7))], w4.w);
        }
        for (int e = E4 + tid; e < E; e += 256) {
            const int r = dst[e] - lo;
            if ((unsigned)r < HALF) {
                const int k = src[e];
                atomicAdd(&Wf[r * SD + ((((k >> 3) ^ (r & 7)) << 3) | (k & 7))], weights[e]);
            }
        }
        __syncthreads();

        if ((wave >> 1) == ph) {
            const int wl = wave & 1;
            #pragma unroll
            for (int mt = 0; mt < 2; ++mt) {
                const int rr = wl * 32 + mt * 16 + lr;
                #pragma unroll
                for (int kt = 0; kt < 4; ++kt) {
                    const int g = (kt * 4 + kq) ^ (rr & 7);
                    const float* p = Wf + rr * SD + g * 8;
                    const f32x4 x = *reinterpret_cast<const f32x4*>(p);
                    const f32x4 y = *reinterpret_cast<const f32x4*>(p + 4);
                    u32x4 v;
                    v.x = f2bf(x[0]) | (f2bf(x[1]) << 16);
                    v.y = f2bf(x[2]) | (f2bf(x[3]) << 16);
                    v.z = f2bf(y[0]) | (f2bf(y[1]) << 16);
                    v.w = f2bf(y[2]) | (f2bf(y[3]) << 16);
                    areg[mt][kt] = v;
                }
            }
        }
    }
    __syncthreads();

    f32x4 acc[2][4] = {};
    #pragma unroll
    for (int kt = 0; kt < 4; ++kt) {
        bf16x8 bf[4];
        #pragma unroll
        for (int nt = 0; nt < 4; ++nt) {
            const int c = nt * 16 + lr;
            const int g = (kt * 4 + kq) ^ (c & 7);
            bf[nt] = *reinterpret_cast<const bf16x8*>(Ft + c * SD + g * 8);
        }
        #pragma unroll
        for (int mt = 0; mt < 2; ++mt) {
            const bf16x8 af = __builtin_bit_cast(bf16x8, areg[mt][kt]);
            #pragma unroll
            for (int nt = 0; nt < 4; ++nt)
                acc[mt][nt] = __builtin_amdgcn_mfma_f32_16x16x32_bf16(
                    af, bf[nt], acc[mt][nt], 0, 0, 0);
        }
    }

    #pragma unroll
    for (int mt = 0; mt < 2; ++mt) {
        const int nbase = wave * 32 + mt * 16 + kq * 4;
        #pragma unroll
        for (int nt = 0; nt < 4; ++nt) {
            const int d = col0 + nt * 16 + lr;
            #pragma unroll
            for (int r = 0; r < 4; ++r)
                out[(size_t)(nbase + r) * DCOLS + d] = acc[mt][nt][r];
        }
    }
}

extern "C" void kernel_launch(void* const* d_in, const int* in_sizes, int n_in,
                              void* d_out, int out_size, void* d_ws, size_t ws_size,
                              hipStream_t stream) {
    const float* loss    = (const float*)d_in[0];
    const float* prev    = (const float*)d_in[1];
    const float* params  = (const float*)d_in[2];
    const float* weights = (const float*)d_in[3];
    const int*   src     = (const int*)d_in[4];
    const int*   dst     = (const int*)d_in[5];
    float*       out     = (float*)d_out;

    const int E = in_sizes[3];              // 4096
    const int P = in_sizes[2] / DCOLS;      // 126
    const int S = 2 + P;                    // 128

    fused_edges_mfma<<<DCOLS / NB, 256, 0, stream>>>(
        loss, prev, params, weights, src, dst, out, E, S);
}